// Round 7
// baseline (470.746 us; speedup 1.0000x reference)
//
#include <hip/hip_runtime.h>
#include <math.h>

#define N_NODES 661
#define N_GRAPH 128
#define DEG 8
#define EPG (N_NODES*DEG)          // 5288 edges per graph per matrix
#define NTOT (N_NODES*N_GRAPH)     // 84608 nodes
#define FDIM 64
#define NF ((size_t)NTOT*FDIM)     // elements per [n,64] array
#define OSTR 672                   // padded CSR offsets stride
#define NTILE 11
#define TROWS 61                   // 11*61 = 671 >= 661
#define PACKB 1024                 // pack blocks in prep_pack

using short8  = __attribute__((ext_vector_type(8))) short;
using float4v = __attribute__((ext_vector_type(4))) float;

__device__ __forceinline__ unsigned short f2bf(float x) {
    unsigned int u = __float_as_uint(x);
    unsigned int r = u + 0x7FFFu + ((u >> 16) & 1u);
    return (unsigned short)(r >> 16);
}
__device__ __forceinline__ float bf2f(unsigned short h) {
    return __uint_as_float(((unsigned int)h) << 16);
}
// pack float into (bf16_hi << 16) | bf16_lo residual
__device__ __forceinline__ unsigned pack_bf(float x) {
    unsigned short h = f2bf(x);
    unsigned short l = f2bf(x - bf2f(h));
    return ((unsigned)h << 16) | (unsigned)l;
}

// ---------------------------------------------------------------------------
// Kernel 0: prep_pack — LDS-FREE streaming kernel. blocks 0..79: wtrans
// (bf16 hi/lo W fragments in MFMA B-layout). blocks 80..: pack e/f into
// efh=(bf16e_hi<<16)|bf16f_hi and eflo=(bf16e_lo<<16)|bf16f_lo.
// ---------------------------------------------------------------------------
__global__ __launch_bounds__(256) void prep_pack(
    const float* __restrict__ W1, const float* __restrict__ W2,
    const float* __restrict__ e, const float* __restrict__ f,
    unsigned short* __restrict__ Wb1h, unsigned short* __restrict__ Wb1l,
    unsigned short* __restrict__ Wb2h, unsigned short* __restrict__ Wb2l,
    unsigned* __restrict__ efh, unsigned* __restrict__ eflo)
{
    int bid = blockIdx.x;
    int tid = threadIdx.x;

    if (bid < 80) {                       // ---- wtrans part ----
        int i = bid*256 + tid;            // 0..20479
        int j    = i & 7;
        int lane = (i >> 3) & 63;
        int ot   = (i >> 9) & 3;
        int ks   = i >> 11;
        int k = ks*32 + (lane >> 4)*8 + j;
        int o = ot*16 + (lane & 15);
        float w1 = W1[o*320 + k];
        float w2 = W2[o*320 + k];
        unsigned short h1 = f2bf(w1); Wb1h[i] = h1; Wb1l[i] = f2bf(w1 - bf2f(h1));
        unsigned short h2 = f2bf(w2); Wb2h[i] = h2; Wb2l[i] = f2bf(w2 - bf2f(h2));
        return;
    }

    // ---- ef bf16 hi/lo pair pack ----
    const int nf4 = (int)(NF/4);
    int i0 = (bid - 80)*256 + tid;
    const int stride = PACKB*256;
    const float4v* e4 = (const float4v*)e;
    const float4v* f4 = (const float4v*)f;
    uint4* oh = (uint4*)efh;
    uint4* ol = (uint4*)eflo;
    for (int i = i0; i < nf4; i += stride) {
        float4v ev = e4[i];
        float4v fv = f4[i];
        uint4 uh, ul;
        unsigned short h, l;
        #define PK(idx, FLD) \
            h = f2bf(ev[idx]); l = f2bf(ev[idx] - bf2f(h)); \
            uh.FLD = ((unsigned)h << 16); ul.FLD = ((unsigned)l << 16); \
            h = f2bf(fv[idx]); l = f2bf(fv[idx] - bf2f(h)); \
            uh.FLD |= (unsigned)h; ul.FLD |= (unsigned)l;
        PK(0, x) PK(1, y) PK(2, z) PK(3, w)
        #undef PK
        oh[i] = uh;
        ol[i] = ul;
    }
}

// ---------------------------------------------------------------------------
// Kernel 1: csr_build (round-1 proven sorter, sort-ONLY, 512 blocks):
// per-(graph,matrix) LDS counting sort -> CSR.
// ---------------------------------------------------------------------------
__global__ __launch_bounds__(256) void csr_build(
    const int* __restrict__ rG, const int* __restrict__ cG, const float* __restrict__ vG,
    const int* __restrict__ rB, const int* __restrict__ cB, const float* __restrict__ vB,
    const int* __restrict__ r1, const int* __restrict__ c1, const float* __restrict__ v1,
    const int* __restrict__ r2, const int* __restrict__ c2, const float* __restrict__ v2,
    int* __restrict__ offs_out, int2* __restrict__ pairs_out)
{
    __shared__ int   scount[N_NODES];
    __shared__ int   soffs[N_NODES+1];
    __shared__ int   scursor[N_NODES];
    __shared__ int   scol[EPG];
    __shared__ float sval[EPG];
    __shared__ int   sscan[256];

    int bid = blockIdx.x;
    int tid = threadIdx.x;
    int g = bid & 127;
    int m = bid >> 7;
    const int*   rows = (m==0)?rG:(m==1)?rB:(m==2)?r1:r2;
    const int*   cols = (m==0)?cG:(m==1)?cB:(m==2)?c1:c2;
    const float* vals = (m==0)?vG:(m==1)?vB:(m==2)?v1:v2;

    int ebase = g*EPG;
    int gbase = g*N_NODES;
    int seg = m*N_GRAPH + g;

    for (int i = tid; i < N_NODES; i += 256) scount[i] = 0;
    __syncthreads();
    for (int i = tid; i < EPG; i += 256)
        atomicAdd(&scount[rows[ebase+i] - gbase], 1);
    __syncthreads();

    int c0 = tid*3;
    int ps = 0;
    #pragma unroll
    for (int j = 0; j < 3; ++j) { int i = c0+j; if (i < N_NODES) ps += scount[i]; }
    sscan[tid] = ps;
    __syncthreads();
    #pragma unroll
    for (int d = 1; d < 256; d <<= 1) {
        int v = (tid >= d) ? sscan[tid-d] : 0;
        __syncthreads();
        sscan[tid] += v;
        __syncthreads();
    }
    int run = sscan[tid] - ps;   // exclusive prefix
    #pragma unroll
    for (int j = 0; j < 3; ++j) {
        int i = c0+j;
        if (i < N_NODES) { soffs[i] = run; scursor[i] = run; run += scount[i]; }
    }
    if (tid == 0) soffs[N_NODES] = EPG;
    __syncthreads();

    for (int i = tid; i < EPG; i += 256) {
        int r = rows[ebase+i] - gbase;
        int pos = atomicAdd(&scursor[r], 1);
        scol[pos] = cols[ebase+i];
        sval[pos] = vals[ebase+i];
    }
    __syncthreads();

    for (int i = tid; i <= N_NODES; i += 256)
        offs_out[(size_t)seg*OSTR + i] = soffs[i];
    int2* po = pairs_out + (size_t)seg*EPG;
    for (int i = tid; i < EPG; i += 256)
        po[i] = make_int2(scol[i], __float_as_int(sval[i]));
}

// ---------------------------------------------------------------------------
__device__ __forceinline__ void node_math1(
    float ev, float fv, float gd, float bd, float pd, float qd,
    float eGv, float fGv, float eBv, float fBv,
    float& e3v, float& nev, float& f3v, float& nfv)
{
    float invb = 1.0f/(ev*ev + fv*fv + 0.1f);
    float alpha = (pd*ev + qd*fv)*invb - eGv - fBv;
    float beta  = (qd*ev - pd*fv)*invb + fGv + eBv;
    float invg = 1.0f/(gd*gd + bd*bd);
    e3v = (alpha*gd + beta*bd)*invg;
    f3v = (beta*gd - alpha*bd)*invg;
    float bb1 = eGv - fBv, bb2 = fGv + eBv;
    float vv = ev*ev + fv*fv;
    float P_ = pd - vv*gd, Q_ = qd + vv*bd;
    nev = (P_*bb1 + Q_*bb2)*invg;
    nfv = (P_*bb2 - Q_*bb1)*invg;
}

// ---------------------------------------------------------------------------
// Kernel 2: gather SpMM (round-1 proven, 162 us). lane = feature; one packed
// bf16-pair dword gather per edge. A and B matrix batches interleaved.
// arrs: [0]=e3 [1]=ne [2]=e1 [3]=e2 [4]=f3 [5]=nf [6]=f1 [7]=f2
// Grid: 2816 = 8 XCD * 16 graphs * 22 (11 tiles x 2 sets).
// ---------------------------------------------------------------------------
__global__ __launch_bounds__(256) void gather_all(
    const float* __restrict__ e, const float* __restrict__ f,
    const unsigned* __restrict__ efh,
    const float* __restrict__ Gd, const float* __restrict__ Bd,
    const float* __restrict__ Pd, const float* __restrict__ Qd,
    const float* __restrict__ w_ae, const float* __restrict__ w_af,
    const int* __restrict__ offs, const int2* __restrict__ pairs,
    unsigned* __restrict__ arrs, float* __restrict__ partials)
{
    int tid = threadIdx.x, lane = tid & 63, wv = tid >> 6;
    int bid = blockIdx.x;
    int xcd = bid & 7, loc = bid >> 3;          // loc 0..351
    int g    = xcd*16 + loc/22;
    int sub  = loc % 22;
    int set  = (sub < NTILE) ? 0 : 1;
    int tile = sub - set*NTILE;
    int r0   = tile*TROWS;
    int rlim = min(TROWS, N_NODES - r0);
    int mA = set ? 2 : 0, mB = set ? 3 : 1;

    const int*  poA = offs + (size_t)(mA*N_GRAPH + g)*OSTR;
    const int*  poB = offs + (size_t)(mB*N_GRAPH + g)*OSTR;
    const int2* ppA = pairs + (size_t)(mA*N_GRAPH + g)*EPG;
    const int2* ppB = pairs + (size_t)(mB*N_GRAPH + g)*EPG;

    float wa = w_ae[lane], wf = w_af[lane];
    float pa0 = 0.f, pa1 = 0.f, pa2 = 0.f, pa3 = 0.f;

    for (int lr = wv; lr < rlim; lr += 4) {
        int r = r0 + lr;
        int node = g*N_NODES + r;
        int sA = __builtin_amdgcn_readfirstlane(poA[r]);
        int tA = __builtin_amdgcn_readfirstlane(poA[r+1]);
        int sB = __builtin_amdgcn_readfirstlane(poB[r]);
        int tB = __builtin_amdgcn_readfirstlane(poB[r+1]);
        int dA = tA - sA, dB = tB - sB;
        int nmax = max(dA, dB);

        float aE = 0.f, aF = 0.f, bE = 0.f, bF = 0.f;

        for (int base = 0; base < nmax; base += 8) {
            int2 pA[8], pB[8];
            #pragma unroll
            for (int j = 0; j < 8; ++j) {
                int k = base + j;
                int iA = (k < dA) ? (sA + k) : (sA ? sA - 1 : 0);
                int iB = (k < dB) ? (sB + k) : (sB ? sB - 1 : 0);
                pA[j] = ppA[iA];
                pB[j] = ppB[iB];
            }
            unsigned uA[8], uB[8];
            #pragma unroll
            for (int j = 0; j < 8; ++j) {
                unsigned oA = ((unsigned)pA[j].x << 6) + (unsigned)lane;
                unsigned oB = ((unsigned)pB[j].x << 6) + (unsigned)lane;
                uA[j] = efh[oA];
                uB[j] = efh[oB];
            }
            #pragma unroll
            for (int j = 0; j < 8; ++j) {
                int k = base + j;
                float vA = (k < dA) ? __int_as_float(pA[j].y) : 0.f;
                float vB = (k < dB) ? __int_as_float(pB[j].y) : 0.f;
                float evA = __uint_as_float(uA[j] & 0xFFFF0000u);
                float fvA = __uint_as_float(uA[j] << 16);
                float evB = __uint_as_float(uB[j] & 0xFFFF0000u);
                float fvB = __uint_as_float(uB[j] << 16);
                aE = fmaf(vA, evA, aE); aF = fmaf(vA, fvA, aF);
                bE = fmaf(vB, evB, bE); bF = fmaf(vB, fvB, bF);
            }
        }

        size_t idx = (size_t)node*FDIM + lane;
        if (set == 0) {
            float ev = e[idx], fv = f[idx];
            float gd = Gd[node], bd = Bd[node], pd = Pd[node], qd = Qd[node];
            float e3v, nev, f3v, nfv;
            node_math1(ev, fv, gd, bd, pd, qd, aE, aF, bE, bF, e3v, nev, f3v, nfv);
            arrs[0*NF + idx] = pack_bf(e3v);
            arrs[1*NF + idx] = pack_bf(nev);
            arrs[4*NF + idx] = pack_bf(f3v);
            arrs[5*NF + idx] = pack_bf(nfv);
            pa0 += e3v*wa; pa1 += nev*wa; pa2 += f3v*wf; pa3 += nfv*wf;
        } else {
            arrs[2*NF + idx] = pack_bf(aE);   // e1
            arrs[3*NF + idx] = pack_bf(bE);   // e2
            arrs[6*NF + idx] = pack_bf(aF);   // f1
            arrs[7*NF + idx] = pack_bf(bF);   // f2
            pa0 += aE*wa; pa1 += bE*wa; pa2 += aF*wf; pa3 += bF*wf;
        }
    }

    __shared__ float sred[4];
    if (tid < 4) sred[tid] = 0.f;
    __syncthreads();
    #pragma unroll
    for (int off = 32; off > 0; off >>= 1) {
        pa0 += __shfl_down(pa0, off); pa1 += __shfl_down(pa1, off);
        pa2 += __shfl_down(pa2, off); pa3 += __shfl_down(pa3, off);
    }
    if (lane == 0) {
        atomicAdd(&sred[0], pa0); atomicAdd(&sred[1], pa1);
        atomicAdd(&sred[2], pa2); atomicAdd(&sred[3], pa3);
    }
    __syncthreads();
    if (tid == 0) {
        float* pt = partials + ((size_t)g*NTILE + tile)*8;
        if (set == 0) { pt[0] = sred[0]; pt[1] = sred[1]; pt[4] = sred[2]; pt[5] = sred[3]; }
        else          { pt[2] = sred[0]; pt[3] = sred[1]; pt[6] = sred[2]; pt[7] = sred[3]; }
    }
}

// ---------------------------------------------------------------------------
// Kernel 3: finalize attention weights (normalized)
// ---------------------------------------------------------------------------
__global__ void attn_final(const float* __restrict__ partials,
                           const float* __restrict__ b_ae, const float* __restrict__ b_af,
                           float* __restrict__ att)
{
    int g = threadIdx.x;
    if (g >= N_GRAPH) return;
    float s[8];
    #pragma unroll
    for (int j = 0; j < 8; ++j) {
        float t = 0.f;
        for (int q = 0; q < NTILE; ++q) t += partials[((size_t)g*NTILE + q)*8 + j];
        s[j] = t;
    }
    float ae[4], af[4], se = 1e-4f, sf = 1e-4f;
    float bae = b_ae[0], baf = b_af[0];
    #pragma unroll
    for (int j = 0; j < 4; ++j) {
        float x = s[j]*(1.0f/N_NODES) + bae;
        ae[j] = 1.0f/(1.0f + expf(-x)); se += ae[j];
        float y = s[4+j]*(1.0f/N_NODES) + baf;
        af[j] = 1.0f/(1.0f + expf(-y)); sf += af[j];
    }
    #pragma unroll
    for (int j = 0; j < 4; ++j) {
        att[g*8 + j]     = ae[j]/se;
        att[g*8 + 4 + j] = af[j]/sf;
    }
}

// ---------------------------------------------------------------------------
// Kernel 4: MFMA epilogue v6 — direct-load (R3 structure, 0 bank conflicts)
// + explicit depth-1 software prefetch: unit u+1's four A-uint4 loads issue
// BEFORE unit u's unpack+MFMA, double-buffered in named regs (fully unrolled,
// compile-time indices). __launch_bounds__(256,4) -> <=128 VGPR, 4 waves/SIMD.
// 10 units = (seg 0..4) x (ks2 0..1); seg<4 from arrs, seg==4 from efh/eflo.
// ---------------------------------------------------------------------------
__global__ __launch_bounds__(256, 4) void final_fused(
    const unsigned* __restrict__ efh, const unsigned* __restrict__ eflo,
    const unsigned* __restrict__ arrs,
    const float* __restrict__ att,
    const unsigned short* __restrict__ Wb1h, const unsigned short* __restrict__ Wb1l,
    const unsigned short* __restrict__ Wb2h, const unsigned short* __restrict__ Wb2l,
    const float* __restrict__ bv1, const float* __restrict__ bv2,
    float* __restrict__ out)
{
    int tid = threadIdx.x, lane = tid & 63, wv = tid >> 6;
    int m16 = lane & 15, quad = lane >> 4;
    int node0 = blockIdx.x * 16;
    size_t rowbase = (size_t)(node0 + m16)*FDIM + (unsigned)quad*8;

    float4v acce[5], accf[5];
    #pragma unroll
    for (int s = 0; s < 5; ++s) {
        acce[s] = (float4v){0.f,0.f,0.f,0.f};
        accf[s] = (float4v){0.f,0.f,0.f,0.f};
    }

    uint4 pbuf[2][4];

    // Load A-fragments for unit u into slot s. Unit u: seg=u>>1, ks2=u&1.
    #define LOADA(u, s)                                                         \
    {                                                                           \
        int seg_ = (u) >> 1, ks2_ = (u) & 1;                                    \
        const unsigned *p0_, *p1_;                                              \
        if (seg_ < 4) {                                                         \
            p0_ = arrs + (size_t)seg_*NF     + rowbase + ks2_*32;               \
            p1_ = arrs + (size_t)(seg_+4)*NF + rowbase + ks2_*32;               \
        } else {                                                                \
            p0_ = efh  + rowbase + ks2_*32;                                     \
            p1_ = eflo + rowbase + ks2_*32;                                     \
        }                                                                       \
        pbuf[s][0] = *(const uint4*)p0_;                                        \
        pbuf[s][1] = *(const uint4*)(p0_ + 4);                                  \
        pbuf[s][2] = *(const uint4*)p1_;                                        \
        pbuf[s][3] = *(const uint4*)(p1_ + 4);                                  \
    }

    LOADA(0, 0)

    #pragma unroll
    for (int u = 0; u < 10; ++u) {
        if (u < 9) LOADA(u+1, (u+1) & 1)

        int seg = u >> 1;
        size_t boff = (size_t)((u*4 + wv)*64 + lane)*8;
        short8 bh1 = *(const short8*)(Wb1h + boff);
        short8 bl1 = *(const short8*)(Wb1l + boff);
        short8 bh2 = *(const short8*)(Wb2h + boff);
        short8 bl2 = *(const short8*)(Wb2l + boff);

        const uint4* P = pbuf[u & 1];
        unsigned u0[8] = {P[0].x,P[0].y,P[0].z,P[0].w,P[1].x,P[1].y,P[1].z,P[1].w};
        unsigned u1[8] = {P[2].x,P[2].y,P[2].z,P[2].w,P[3].x,P[3].y,P[3].z,P[3].w};
        short8 ah, al, ch, cl;
        if (seg < 4) {
            // u0 = e-array packed hi|lo, u1 = f-array packed hi|lo
            #pragma unroll
            for (int j = 0; j < 8; ++j) {
                ah[j] = (short)(u0[j] >> 16);
                al[j] = (short)(u0[j] & 0xFFFFu);
                ch[j] = (short)(u1[j] >> 16);
                cl[j] = (short)(u1[j] & 0xFFFFu);
            }
        } else {
            // u0 = efh (e_hi|f_hi), u1 = eflo (e_lo|f_lo)
            #pragma unroll
            for (int j = 0; j < 8; ++j) {
                ah[j] = (short)(u0[j] >> 16);        // e hi
                al[j] = (short)(u1[j] >> 16);        // e lo
                ch[j] = (short)(u0[j] & 0xFFFFu);    // f hi
                cl[j] = (short)(u1[j] & 0xFFFFu);    // f lo
            }
        }

        acce[seg] = __builtin_amdgcn_mfma_f32_16x16x32_bf16(ah, bh1, acce[seg], 0, 0, 0);
        acce[seg] = __builtin_amdgcn_mfma_f32_16x16x32_bf16(al, bh1, acce[seg], 0, 0, 0);
        acce[seg] = __builtin_amdgcn_mfma_f32_16x16x32_bf16(ah, bl1, acce[seg], 0, 0, 0);
        accf[seg] = __builtin_amdgcn_mfma_f32_16x16x32_bf16(ch, bh2, accf[seg], 0, 0, 0);
        accf[seg] = __builtin_amdgcn_mfma_f32_16x16x32_bf16(cl, bh2, accf[seg], 0, 0, 0);
        accf[seg] = __builtin_amdgcn_mfma_f32_16x16x32_bf16(ch, bl2, accf[seg], 0, 0, 0);
    }
    #undef LOADA

    // ---- epilogue: normalized att (uniform scalar loads), tanh, store ----
    int g0 = node0 / N_NODES;
    int nb = (g0+1)*N_NODES;
    int g1 = min(g0+1, N_GRAPH-1);
    float wE0[4], wF0[4], wE1[4], wF1[4];
    #pragma unroll
    for (int b = 0; b < 4; ++b) {
        wE0[b] = att[g0*8 + b];  wF0[b] = att[g0*8 + 4 + b];
        wE1[b] = att[g1*8 + b];  wF1[b] = att[g1*8 + 4 + b];
    }

    int o = wv*16 + m16;
    float be = bv1[o], bf = bv2[o];
    #pragma unroll
    for (int reg = 0; reg < 4; ++reg) {
        int node = node0 + quad*4 + reg;
        bool hi = node >= nb;
        float se2 = acce[4][reg];
        float sf2 = accf[4][reg];
        #pragma unroll
        for (int b = 0; b < 4; ++b) {
            se2 = fmaf(hi ? wE1[b] : wE0[b], acce[b][reg], se2);
            sf2 = fmaf(hi ? wF1[b] : wF0[b], accf[b][reg], sf2);
        }
        __builtin_nontemporal_store(tanhf(se2 + be), &out[(size_t)node*FDIM + o]);
        __builtin_nontemporal_store(tanhf(sf2 + bf), &out[NF + (size_t)node*FDIM + o]);
    }
}

// ---------------------------------------------------------------------------
extern "C" void kernel_launch(void* const* d_in, const int* in_sizes, int n_in,
                              void* d_out, int out_size, void* d_ws, size_t ws_size,
                              hipStream_t stream) {
    (void)in_sizes; (void)n_in; (void)out_size; (void)ws_size;
    const float* e     = (const float*)d_in[0];
    const float* f     = (const float*)d_in[1];
    const int*   rowsG = (const int*)d_in[2];
    const int*   colsG = (const int*)d_in[3];
    const float* valsG = (const float*)d_in[4];
    const int*   rowsB = (const int*)d_in[5];
    const int*   colsB = (const int*)d_in[6];
    const float* valsB = (const float*)d_in[7];
    const int*   rows1 = (const int*)d_in[8];
    const int*   cols1 = (const int*)d_in[9];
    const float* vals1 = (const float*)d_in[10];
    const int*   rows2 = (const int*)d_in[11];
    const int*   cols2 = (const int*)d_in[12];
    const float* vals2 = (const float*)d_in[13];
    const float* G_d   = (const float*)d_in[14];
    const float* B_d   = (const float*)d_in[15];
    const float* Pd    = (const float*)d_in[16];
    const float* Qd    = (const float*)d_in[17];
    const float* W1    = (const float*)d_in[18];
    const float* b1    = (const float*)d_in[19];
    const float* W2    = (const float*)d_in[20];
    const float* b2    = (const float*)d_in[21];
    const float* w_ae  = (const float*)d_in[22];
    const float* b_ae  = (const float*)d_in[23];
    const float* w_af  = (const float*)d_in[24];
    const float* b_af  = (const float*)d_in[25];

    unsigned* arrs  = (unsigned*)d_ws;               // 8*NF uints (packed bf16 h|l)
    float* partials = (float*)(arrs + 8*NF);         // 128*11*8 = 11264
    float* att      = partials + 11264;              // 1024 (normalized weights)
    unsigned short* Wb1h = (unsigned short*)(att + 1024);  // 20480 shorts each
    unsigned short* Wb1l = Wb1h + 20480;
    unsigned short* Wb2h = Wb1l + 20480;
    unsigned short* Wb2l = Wb2h + 20480;
    int*   offs     = (int*)(Wb2l + 20480);          // 512*OSTR ints
    int2*  pairs    = (int2*)(offs + 512*OSTR);      // 512*EPG int2
    unsigned* efh   = (unsigned*)(pairs + (size_t)512*EPG);  // NF uints (bf16 e|f hi)
    unsigned* eflo  = efh + NF;                      // NF uints (bf16 e|f lo)

    prep_pack<<<dim3(80 + PACKB), dim3(256), 0, stream>>>(
        W1, W2, e, f, Wb1h, Wb1l, Wb2h, Wb2l, efh, eflo);

    csr_build<<<dim3(512), dim3(256), 0, stream>>>(
        rowsG, colsG, valsG, rowsB, colsB, valsB,
        rows1, cols1, vals1, rows2, cols2, vals2, offs, pairs);

    gather_all<<<dim3(2816), dim3(256), 0, stream>>>(
        e, f, efh, G_d, B_d, Pd, Qd, w_ae, w_af, offs, pairs, arrs, partials);

    attn_final<<<dim3(1), dim3(128), 0, stream>>>(partials, b_ae, b_af, att);

    final_fused<<<dim3(NTOT/16), dim3(256), 0, stream>>>(
        efh, eflo, arrs, att, Wb1h, Wb1l, Wb2h, Wb2l, b1, b2, (float*)d_out);
}

// Round 8
// 386.029 us; speedup vs baseline: 1.2195x; 1.2195x over previous
//
#include <hip/hip_runtime.h>
#include <math.h>

#define N_NODES 661
#define N_GRAPH 128
#define DEG 8
#define EPG (N_NODES*DEG)          // 5288 edges per graph per matrix
#define NTOT (N_NODES*N_GRAPH)     // 84608 nodes
#define FDIM 64
#define NF ((size_t)NTOT*FDIM)     // elements per [n,64] array
#define OSTR 672                   // padded CSR offsets stride
#define NTILE 11
#define TROWS 61                   // 11*61 = 671 >= 661
#define PACKB 1024                 // pack blocks in prep_pack

using short8  = __attribute__((ext_vector_type(8))) short;
using float4v = __attribute__((ext_vector_type(4))) float;

__device__ __forceinline__ unsigned short f2bf(float x) {
    unsigned int u = __float_as_uint(x);
    unsigned int r = u + 0x7FFFu + ((u >> 16) & 1u);
    return (unsigned short)(r >> 16);
}
__device__ __forceinline__ float bf2f(unsigned short h) {
    return __uint_as_float(((unsigned int)h) << 16);
}
// pack float into (bf16_hi << 16) | bf16_lo residual
__device__ __forceinline__ unsigned pack_bf(float x) {
    unsigned short h = f2bf(x);
    unsigned short l = f2bf(x - bf2f(h));
    return ((unsigned)h << 16) | (unsigned)l;
}

// ---------------------------------------------------------------------------
// Kernel 0: prep_pack — LDS-FREE streaming kernel. blocks 0..79: wtrans
// (bf16 hi/lo W fragments in MFMA B-layout). blocks 80..: pack ef into
// (bf16(e)<<16)|bf16(f) words for the gather kernel.
// ---------------------------------------------------------------------------
__global__ __launch_bounds__(256) void prep_pack(
    const float* __restrict__ W1, const float* __restrict__ W2,
    const float* __restrict__ e, const float* __restrict__ f,
    unsigned short* __restrict__ Wb1h, unsigned short* __restrict__ Wb1l,
    unsigned short* __restrict__ Wb2h, unsigned short* __restrict__ Wb2l,
    unsigned* __restrict__ efh)
{
    int bid = blockIdx.x;
    int tid = threadIdx.x;

    if (bid < 80) {                       // ---- wtrans part ----
        int i = bid*256 + tid;            // 0..20479
        int j    = i & 7;
        int lane = (i >> 3) & 63;
        int ot   = (i >> 9) & 3;
        int ks   = i >> 11;
        int k = ks*32 + (lane >> 4)*8 + j;
        int o = ot*16 + (lane & 15);
        float w1 = W1[o*320 + k];
        float w2 = W2[o*320 + k];
        unsigned short h1 = f2bf(w1); Wb1h[i] = h1; Wb1l[i] = f2bf(w1 - bf2f(h1));
        unsigned short h2 = f2bf(w2); Wb2h[i] = h2; Wb2l[i] = f2bf(w2 - bf2f(h2));
        return;
    }

    // ---- ef bf16-pair pack ----
    const int nf4 = (int)(NF/4);
    int i0 = (bid - 80)*256 + tid;
    const int stride = PACKB*256;
    const float4v* e4 = (const float4v*)e;
    const float4v* f4 = (const float4v*)f;
    uint4* o4 = (uint4*)efh;
    for (int i = i0; i < nf4; i += stride) {
        float4v ev = e4[i];
        float4v fv = f4[i];
        uint4 u;
        u.x = ((unsigned)f2bf(ev[0]) << 16) | (unsigned)f2bf(fv[0]);
        u.y = ((unsigned)f2bf(ev[1]) << 16) | (unsigned)f2bf(fv[1]);
        u.z = ((unsigned)f2bf(ev[2]) << 16) | (unsigned)f2bf(fv[2]);
        u.w = ((unsigned)f2bf(ev[3]) << 16) | (unsigned)f2bf(fv[3]);
        o4[i] = u;
    }
}

// ---------------------------------------------------------------------------
// Kernel 1: csr_build v2 — 1024 threads/block (was 256). 4x waves/CU
// (2 blocks x 16 waves = 32 waves/CU vs 8), edge loops 5.2 iters (was 21),
// and the 661-wide prefix scan is a 3-barrier two-level wave scan
// (shfl_up within wave -> 16 wave-sums scanned by wave 0 -> add back)
// replacing the 16-barrier Hillis-Steele over 256 threads.
// ---------------------------------------------------------------------------
__global__ __launch_bounds__(1024) void csr_build(
    const int* __restrict__ rG, const int* __restrict__ cG, const float* __restrict__ vG,
    const int* __restrict__ rB, const int* __restrict__ cB, const float* __restrict__ vB,
    const int* __restrict__ r1, const int* __restrict__ c1, const float* __restrict__ v1,
    const int* __restrict__ r2, const int* __restrict__ c2, const float* __restrict__ v2,
    int* __restrict__ offs_out, int2* __restrict__ pairs_out)
{
    __shared__ int   scount[N_NODES];
    __shared__ int   soffs[N_NODES+1];
    __shared__ int   scursor[N_NODES];
    __shared__ int   scol[EPG];
    __shared__ float sval[EPG];
    __shared__ int   swsum[16];
    __shared__ int   swoff[16];

    int bid = blockIdx.x;
    int tid = threadIdx.x;
    int lane = tid & 63, w = tid >> 6;
    int g = bid & 127;
    int m = bid >> 7;
    const int*   rows = (m==0)?rG:(m==1)?rB:(m==2)?r1:r2;
    const int*   cols = (m==0)?cG:(m==1)?cB:(m==2)?c1:c2;
    const float* vals = (m==0)?vG:(m==1)?vB:(m==2)?v1:v2;

    int ebase = g*EPG;
    int gbase = g*N_NODES;
    int seg = m*N_GRAPH + g;

    if (tid < N_NODES) scount[tid] = 0;
    __syncthreads();
    for (int i = tid; i < EPG; i += 1024)
        atomicAdd(&scount[rows[ebase+i] - gbase], 1);
    __syncthreads();

    // two-level exclusive scan over 1024 slots (scount[i] for i<661, else 0)
    int cnt = (tid < N_NODES) ? scount[tid] : 0;
    int v = cnt;
    #pragma unroll
    for (int d = 1; d < 64; d <<= 1) {
        int t = __shfl_up(v, (unsigned)d, 64);
        if (lane >= d) v += t;
    }
    if (lane == 63) swsum[w] = v;
    __syncthreads();
    if (w == 0 && lane < 16) {
        int s = swsum[lane];
        #pragma unroll
        for (int d = 1; d < 16; d <<= 1) {
            int t = __shfl_up(s, (unsigned)d, 16);
            if ((lane & 15) >= d) s += t;
        }
        swoff[lane] = s - swsum[lane];     // exclusive wave offset
    }
    __syncthreads();
    int excl = v - cnt + swoff[w];
    if (tid < N_NODES) { soffs[tid] = excl; scursor[tid] = excl; }
    if (tid == 0) soffs[N_NODES] = EPG;
    __syncthreads();

    for (int i = tid; i < EPG; i += 1024) {
        int r = rows[ebase+i] - gbase;
        int pos = atomicAdd(&scursor[r], 1);
        scol[pos] = cols[ebase+i];
        sval[pos] = vals[ebase+i];
    }
    __syncthreads();

    if (tid <= N_NODES) offs_out[(size_t)seg*OSTR + tid] = soffs[tid];
    int2* po = pairs_out + (size_t)seg*EPG;
    for (int i = tid; i < EPG; i += 1024)
        po[i] = make_int2(scol[i], __float_as_int(sval[i]));
}

// ---------------------------------------------------------------------------
__device__ __forceinline__ void node_math1(
    float ev, float fv, float gd, float bd, float pd, float qd,
    float eGv, float fGv, float eBv, float fBv,
    float& e3v, float& nev, float& f3v, float& nfv)
{
    float invb = 1.0f/(ev*ev + fv*fv + 0.1f);
    float alpha = (pd*ev + qd*fv)*invb - eGv - fBv;
    float beta  = (qd*ev - pd*fv)*invb + fGv + eBv;
    float invg = 1.0f/(gd*gd + bd*bd);
    e3v = (alpha*gd + beta*bd)*invg;
    f3v = (beta*gd - alpha*bd)*invg;
    float bb1 = eGv - fBv, bb2 = fGv + eBv;
    float vv = ev*ev + fv*fv;
    float P_ = pd - vv*gd, Q_ = qd + vv*bd;
    nev = (P_*bb1 + Q_*bb2)*invg;
    nfv = (P_*bb2 - Q_*bb1)*invg;
}

// ---------------------------------------------------------------------------
// Kernel 2: gather SpMM (round-1 proven, 162 us). lane = feature; one packed
// bf16-pair dword gather per edge. A and B matrix batches interleaved.
// arrs: [0]=e3 [1]=ne [2]=e1 [3]=e2 [4]=f3 [5]=nf [6]=f1 [7]=f2
// Grid: 2816 = 8 XCD * 16 graphs * 22 (11 tiles x 2 sets).
// ---------------------------------------------------------------------------
__global__ __launch_bounds__(256) void gather_all(
    const float* __restrict__ e, const float* __restrict__ f,
    const unsigned* __restrict__ efh,
    const float* __restrict__ Gd, const float* __restrict__ Bd,
    const float* __restrict__ Pd, const float* __restrict__ Qd,
    const float* __restrict__ w_ae, const float* __restrict__ w_af,
    const int* __restrict__ offs, const int2* __restrict__ pairs,
    unsigned* __restrict__ arrs, float* __restrict__ partials)
{
    int tid = threadIdx.x, lane = tid & 63, wv = tid >> 6;
    int bid = blockIdx.x;
    int xcd = bid & 7, loc = bid >> 3;          // loc 0..351
    int g    = xcd*16 + loc/22;
    int sub  = loc % 22;
    int set  = (sub < NTILE) ? 0 : 1;
    int tile = sub - set*NTILE;
    int r0   = tile*TROWS;
    int rlim = min(TROWS, N_NODES - r0);
    int mA = set ? 2 : 0, mB = set ? 3 : 1;

    const int*  poA = offs + (size_t)(mA*N_GRAPH + g)*OSTR;
    const int*  poB = offs + (size_t)(mB*N_GRAPH + g)*OSTR;
    const int2* ppA = pairs + (size_t)(mA*N_GRAPH + g)*EPG;
    const int2* ppB = pairs + (size_t)(mB*N_GRAPH + g)*EPG;

    float wa = w_ae[lane], wf = w_af[lane];
    float pa0 = 0.f, pa1 = 0.f, pa2 = 0.f, pa3 = 0.f;

    for (int lr = wv; lr < rlim; lr += 4) {
        int r = r0 + lr;
        int node = g*N_NODES + r;
        int sA = __builtin_amdgcn_readfirstlane(poA[r]);
        int tA = __builtin_amdgcn_readfirstlane(poA[r+1]);
        int sB = __builtin_amdgcn_readfirstlane(poB[r]);
        int tB = __builtin_amdgcn_readfirstlane(poB[r+1]);
        int dA = tA - sA, dB = tB - sB;
        int nmax = max(dA, dB);

        float aE = 0.f, aF = 0.f, bE = 0.f, bF = 0.f;

        for (int base = 0; base < nmax; base += 8) {
            int2 pA[8], pB[8];
            #pragma unroll
            for (int j = 0; j < 8; ++j) {
                int k = base + j;
                int iA = (k < dA) ? (sA + k) : (sA ? sA - 1 : 0);
                int iB = (k < dB) ? (sB + k) : (sB ? sB - 1 : 0);
                pA[j] = ppA[iA];
                pB[j] = ppB[iB];
            }
            unsigned uA[8], uB[8];
            #pragma unroll
            for (int j = 0; j < 8; ++j) {
                unsigned oA = ((unsigned)pA[j].x << 6) + (unsigned)lane;
                unsigned oB = ((unsigned)pB[j].x << 6) + (unsigned)lane;
                uA[j] = efh[oA];
                uB[j] = efh[oB];
            }
            #pragma unroll
            for (int j = 0; j < 8; ++j) {
                int k = base + j;
                float vA = (k < dA) ? __int_as_float(pA[j].y) : 0.f;
                float vB = (k < dB) ? __int_as_float(pB[j].y) : 0.f;
                float evA = __uint_as_float(uA[j] & 0xFFFF0000u);
                float fvA = __uint_as_float(uA[j] << 16);
                float evB = __uint_as_float(uB[j] & 0xFFFF0000u);
                float fvB = __uint_as_float(uB[j] << 16);
                aE = fmaf(vA, evA, aE); aF = fmaf(vA, fvA, aF);
                bE = fmaf(vB, evB, bE); bF = fmaf(vB, fvB, bF);
            }
        }

        size_t idx = (size_t)node*FDIM + lane;
        if (set == 0) {
            float ev = e[idx], fv = f[idx];
            float gd = Gd[node], bd = Bd[node], pd = Pd[node], qd = Qd[node];
            float e3v, nev, f3v, nfv;
            node_math1(ev, fv, gd, bd, pd, qd, aE, aF, bE, bF, e3v, nev, f3v, nfv);
            arrs[0*NF + idx] = pack_bf(e3v);
            arrs[1*NF + idx] = pack_bf(nev);
            arrs[4*NF + idx] = pack_bf(f3v);
            arrs[5*NF + idx] = pack_bf(nfv);
            pa0 += e3v*wa; pa1 += nev*wa; pa2 += f3v*wf; pa3 += nfv*wf;
        } else {
            arrs[2*NF + idx] = pack_bf(aE);   // e1
            arrs[3*NF + idx] = pack_bf(bE);   // e2
            arrs[6*NF + idx] = pack_bf(aF);   // f1
            arrs[7*NF + idx] = pack_bf(bF);   // f2
            pa0 += aE*wa; pa1 += bE*wa; pa2 += aF*wf; pa3 += bF*wf;
        }
    }

    __shared__ float sred[4];
    if (tid < 4) sred[tid] = 0.f;
    __syncthreads();
    #pragma unroll
    for (int off = 32; off > 0; off >>= 1) {
        pa0 += __shfl_down(pa0, off); pa1 += __shfl_down(pa1, off);
        pa2 += __shfl_down(pa2, off); pa3 += __shfl_down(pa3, off);
    }
    if (lane == 0) {
        atomicAdd(&sred[0], pa0); atomicAdd(&sred[1], pa1);
        atomicAdd(&sred[2], pa2); atomicAdd(&sred[3], pa3);
    }
    __syncthreads();
    if (tid == 0) {
        float* pt = partials + ((size_t)g*NTILE + tile)*8;
        if (set == 0) { pt[0] = sred[0]; pt[1] = sred[1]; pt[4] = sred[2]; pt[5] = sred[3]; }
        else          { pt[2] = sred[0]; pt[3] = sred[1]; pt[6] = sred[2]; pt[7] = sred[3]; }
    }
}

// ---------------------------------------------------------------------------
// Kernel 3: finalize attention weights (normalized)
// ---------------------------------------------------------------------------
__global__ void attn_final(const float* __restrict__ partials,
                           const float* __restrict__ b_ae, const float* __restrict__ b_af,
                           float* __restrict__ att)
{
    int g = threadIdx.x;
    if (g >= N_GRAPH) return;
    float s[8];
    #pragma unroll
    for (int j = 0; j < 8; ++j) {
        float t = 0.f;
        for (int q = 0; q < NTILE; ++q) t += partials[((size_t)g*NTILE + q)*8 + j];
        s[j] = t;
    }
    float ae[4], af[4], se = 1e-4f, sf = 1e-4f;
    float bae = b_ae[0], baf = b_af[0];
    #pragma unroll
    for (int j = 0; j < 4; ++j) {
        float x = s[j]*(1.0f/N_NODES) + bae;
        ae[j] = 1.0f/(1.0f + expf(-x)); se += ae[j];
        float y = s[4+j]*(1.0f/N_NODES) + baf;
        af[j] = 1.0f/(1.0f + expf(-y)); sf += af[j];
    }
    #pragma unroll
    for (int j = 0; j < 4; ++j) {
        att[g*8 + j]     = ae[j]/se;
        att[g*8 + 4 + j] = af[j]/sf;
    }
}

// ---------------------------------------------------------------------------
// Kernel 4: MFMA epilogue (round-1/6 proven). Stage packed-bf16 uints into
// LDS in fragment order (10 segs: e3,ne,e1,e2,e | f3,nf,f1,f2,f), unpack
// hi/lo with shifts, 5 per-segment accumulators, att folded post-MFMA,
// tanh + store. LDS slot layout: [seg*8+(feat>>3)][node 0..15][8], stride 132.
// ---------------------------------------------------------------------------
__global__ __launch_bounds__(256) void final_fused(
    const float* __restrict__ e, const float* __restrict__ f,
    const unsigned* __restrict__ arrs, const float* __restrict__ att,
    const unsigned short* __restrict__ Wb1h, const unsigned short* __restrict__ Wb1l,
    const unsigned short* __restrict__ Wb2h, const unsigned short* __restrict__ Wb2l,
    const float* __restrict__ bv1, const float* __restrict__ bv2,
    float* __restrict__ out)
{
    __shared__ __align__(16) unsigned sfrag[80*132];

    int tid = threadIdx.x, lane = tid & 63, chunk = tid >> 6;
    int node0 = blockIdx.x * 16;
    int sl = lane >> 3, jj = lane & 7;

    #pragma unroll
    for (int round = 0; round < 4; ++round) {
        int ni = round*4 + chunk;
        size_t idx = (size_t)(node0 + ni)*FDIM + lane;
        #pragma unroll
        for (int seg = 0; seg < 10; ++seg) {
            unsigned u;
            if (seg == 4)      u = pack_bf(e[idx]);
            else if (seg == 9) u = pack_bf(f[idx]);
            else {
                int a = (seg < 4) ? seg : seg - 1;   // segs 0..3 -> arrs0..3; 5..8 -> arrs4..7
                u = arrs[(size_t)a*NF + idx];
            }
            sfrag[(seg*8 + sl)*132 + ni*8 + jj] = u;
        }
    }
    __syncthreads();

    int m16 = lane & 15, quad = lane >> 4;
    float4v acce[5], accf[5];
    #pragma unroll
    for (int s = 0; s < 5; ++s) {
        acce[s] = (float4v){0.f,0.f,0.f,0.f};
        accf[s] = (float4v){0.f,0.f,0.f,0.f};
    }

    #pragma unroll
    for (int seg = 0; seg < 5; ++seg) {
        #pragma unroll
        for (int ks2 = 0; ks2 < 2; ++ks2) {
            int ks = seg*2 + ks2;
            size_t boff = (size_t)((ks*4 + chunk)*64 + lane)*8;
            // e-side
            {
                const unsigned* pa = &sfrag[(seg*8 + ks2*4 + quad)*132 + m16*8];
                uint4 ua = *(const uint4*)pa;
                uint4 ub = *(const uint4*)(pa + 4);
                unsigned uu[8] = {ua.x,ua.y,ua.z,ua.w,ub.x,ub.y,ub.z,ub.w};
                short8 ah, al;
                #pragma unroll
                for (int j = 0; j < 8; ++j) {
                    ah[j] = (short)(uu[j] >> 16);
                    al[j] = (short)(uu[j] & 0xFFFFu);
                }
                short8 bh = *(const short8*)(Wb1h + boff);
                short8 bl = *(const short8*)(Wb1l + boff);
                acce[seg] = __builtin_amdgcn_mfma_f32_16x16x32_bf16(ah, bh, acce[seg], 0, 0, 0);
                acce[seg] = __builtin_amdgcn_mfma_f32_16x16x32_bf16(al, bh, acce[seg], 0, 0, 0);
                acce[seg] = __builtin_amdgcn_mfma_f32_16x16x32_bf16(ah, bl, acce[seg], 0, 0, 0);
            }
            // f-side
            {
                const unsigned* pa = &sfrag[((seg+5)*8 + ks2*4 + quad)*132 + m16*8];
                uint4 ua = *(const uint4*)pa;
                uint4 ub = *(const uint4*)(pa + 4);
                unsigned uu[8] = {ua.x,ua.y,ua.z,ua.w,ub.x,ub.y,ub.z,ub.w};
                short8 ch, cl;
                #pragma unroll
                for (int j = 0; j < 8; ++j) {
                    ch[j] = (short)(uu[j] >> 16);
                    cl[j] = (short)(uu[j] & 0xFFFFu);
                }
                short8 bh = *(const short8*)(Wb2h + boff);
                short8 bl = *(const short8*)(Wb2l + boff);
                accf[seg] = __builtin_amdgcn_mfma_f32_16x16x32_bf16(ch, bh, accf[seg], 0, 0, 0);
                accf[seg] = __builtin_amdgcn_mfma_f32_16x16x32_bf16(cl, bh, accf[seg], 0, 0, 0);
                accf[seg] = __builtin_amdgcn_mfma_f32_16x16x32_bf16(ch, bl, accf[seg], 0, 0, 0);
            }
        }
    }

    int o = chunk*16 + m16;
    float be = bv1[o], bf = bv2[o];
    #pragma unroll
    for (int reg = 0; reg < 4; ++reg) {
        int node = node0 + quad*4 + reg;
        int g = node / N_NODES;
        float se2 = acce[4][reg];
        float sf2 = accf[4][reg];
        #pragma unroll
        for (int b = 0; b < 4; ++b) {
            se2 = fmaf(att[g*8 + b],     acce[b][reg], se2);
            sf2 = fmaf(att[g*8 + 4 + b], accf[b][reg], sf2);
        }
        out[(size_t)node*FDIM + o]      = tanhf(se2 + be);
        out[NF + (size_t)node*FDIM + o] = tanhf(sf2 + bf);
    }
}

// ---------------------------------------------------------------------------
extern "C" void kernel_launch(void* const* d_in, const int* in_sizes, int n_in,
                              void* d_out, int out_size, void* d_ws, size_t ws_size,
                              hipStream_t stream) {
    (void)in_sizes; (void)n_in; (void)out_size; (void)ws_size;
    const float* e     = (const float*)d_in[0];
    const float* f     = (const float*)d_in[1];
    const int*   rowsG = (const int*)d_in[2];
    const int*   colsG = (const int*)d_in[3];
    const float* valsG = (const float*)d_in[4];
    const int*   rowsB = (const int*)d_in[5];
    const int*   colsB = (const int*)d_in[6];
    const float* valsB = (const float*)d_in[7];
    const int*   rows1 = (const int*)d_in[8];
    const int*   cols1 = (const int*)d_in[9];
    const float* vals1 = (const float*)d_in[10];
    const int*   rows2 = (const int*)d_in[11];
    const int*   cols2 = (const int*)d_in[12];
    const float* vals2 = (const float*)d_in[13];
    const float* G_d   = (const float*)d_in[14];
    const float* B_d   = (const float*)d_in[15];
    const float* Pd    = (const float*)d_in[16];
    const float* Qd    = (const float*)d_in[17];
    const float* W1    = (const float*)d_in[18];
    const float* b1    = (const float*)d_in[19];
    const float* W2    = (const float*)d_in[20];
    const float* b2    = (const float*)d_in[21];
    const float* w_ae  = (const float*)d_in[22];
    const float* b_ae  = (const float*)d_in[23];
    const float* w_af  = (const float*)d_in[24];
    const float* b_af  = (const float*)d_in[25];

    unsigned* arrs  = (unsigned*)d_ws;               // 8*NF uints (packed bf16 h|l)
    float* partials = (float*)(arrs + 8*NF);         // 128*11*8 = 11264
    float* att      = partials + 11264;              // 1024 (normalized weights)
    unsigned short* Wb1h = (unsigned short*)(att + 1024);  // 20480 shorts each
    unsigned short* Wb1l = Wb1h + 20480;
    unsigned short* Wb2h = Wb1l + 20480;
    unsigned short* Wb2l = Wb2h + 20480;
    int*   offs     = (int*)(Wb2l + 20480);          // 512*OSTR ints
    int2*  pairs    = (int2*)(offs + 512*OSTR);      // 512*EPG int2
    unsigned* efh   = (unsigned*)(pairs + (size_t)512*EPG);  // NF uints (bf16 e|f pairs)

    prep_pack<<<dim3(80 + PACKB), dim3(256), 0, stream>>>(
        W1, W2, e, f, Wb1h, Wb1l, Wb2h, Wb2l, efh);

    csr_build<<<dim3(512), dim3(1024), 0, stream>>>(
        rowsG, colsG, valsG, rowsB, colsB, valsB,
        rows1, cols1, vals1, rows2, cols2, vals2, offs, pairs);

    gather_all<<<dim3(2816), dim3(256), 0, stream>>>(
        e, f, efh, G_d, B_d, Pd, Qd, w_ae, w_af, offs, pairs, arrs, partials);

    attn_final<<<dim3(1), dim3(128), 0, stream>>>(partials, b_ae, b_af, att);

    final_fused<<<dim3(NTOT/16), dim3(256), 0, stream>>>(
        e, f, arrs, att, Wb1h, Wb1l, Wb2h, Wb2l, b1, b2, (float*)d_out);
}

// Round 9
// 362.836 us; speedup vs baseline: 1.2974x; 1.0639x over previous
//
#include <hip/hip_runtime.h>
#include <math.h>

#define N_NODES 661
#define N_GRAPH 128
#define DEG 8
#define EPG (N_NODES*DEG)          // 5288 edges per graph per matrix
#define NTOT (N_NODES*N_GRAPH)     // 84608 nodes
#define FDIM 64
#define NF ((size_t)NTOT*FDIM)     // elements per [n,64] array
#define OSTR 672                   // padded CSR offsets stride
#define PSTR 7296                  // padded pairs stride (>= 5288 + 3*661 = 7271)
#define PPAD 7272                  // LDS padded pair capacity
#define NTILE 11
#define TROWS 61                   // 11*61 = 671 >= 661
#define PACKB 1024                 // pack blocks in prep_pack

using short8  = __attribute__((ext_vector_type(8))) short;
using float4v = __attribute__((ext_vector_type(4))) float;

__device__ __forceinline__ unsigned short f2bf(float x) {
    unsigned int u = __float_as_uint(x);
    unsigned int r = u + 0x7FFFu + ((u >> 16) & 1u);
    return (unsigned short)(r >> 16);
}
__device__ __forceinline__ float bf2f(unsigned short h) {
    return __uint_as_float(((unsigned int)h) << 16);
}
// pack float into (bf16_hi << 16) | bf16_lo residual
__device__ __forceinline__ unsigned pack_bf(float x) {
    unsigned short h = f2bf(x);
    unsigned short l = f2bf(x - bf2f(h));
    return ((unsigned)h << 16) | (unsigned)l;
}

// ---------------------------------------------------------------------------
// Kernel 0: prep_pack — LDS-FREE streaming kernel. blocks 0..79: wtrans
// (bf16 hi/lo W fragments in MFMA B-layout). blocks 80..: pack ef into
// (bf16(e)<<16)|bf16(f) words for the gather kernel.
// ---------------------------------------------------------------------------
__global__ __launch_bounds__(256) void prep_pack(
    const float* __restrict__ W1, const float* __restrict__ W2,
    const float* __restrict__ e, const float* __restrict__ f,
    unsigned short* __restrict__ Wb1h, unsigned short* __restrict__ Wb1l,
    unsigned short* __restrict__ Wb2h, unsigned short* __restrict__ Wb2l,
    unsigned* __restrict__ efh)
{
    int bid = blockIdx.x;
    int tid = threadIdx.x;

    if (bid < 80) {                       // ---- wtrans part ----
        int i = bid*256 + tid;            // 0..20479
        int j    = i & 7;
        int lane = (i >> 3) & 63;
        int ot   = (i >> 9) & 3;
        int ks   = i >> 11;
        int k = ks*32 + (lane >> 4)*8 + j;
        int o = ot*16 + (lane & 15);
        float w1 = W1[o*320 + k];
        float w2 = W2[o*320 + k];
        unsigned short h1 = f2bf(w1); Wb1h[i] = h1; Wb1l[i] = f2bf(w1 - bf2f(h1));
        unsigned short h2 = f2bf(w2); Wb2h[i] = h2; Wb2l[i] = f2bf(w2 - bf2f(h2));
        return;
    }

    // ---- ef bf16-pair pack ----
    const int nf4 = (int)(NF/4);
    int i0 = (bid - 80)*256 + tid;
    const int stride = PACKB*256;
    const float4v* e4 = (const float4v*)e;
    const float4v* f4 = (const float4v*)f;
    uint4* o4 = (uint4*)efh;
    for (int i = i0; i < nf4; i += stride) {
        float4v ev = e4[i];
        float4v fv = f4[i];
        uint4 u;
        u.x = ((unsigned)f2bf(ev[0]) << 16) | (unsigned)f2bf(fv[0]);
        u.y = ((unsigned)f2bf(ev[1]) << 16) | (unsigned)f2bf(fv[1]);
        u.z = ((unsigned)f2bf(ev[2]) << 16) | (unsigned)f2bf(fv[2]);
        u.w = ((unsigned)f2bf(ev[3]) << 16) | (unsigned)f2bf(fv[3]);
        o4[i] = u;
    }
}

// ---------------------------------------------------------------------------
// Kernel 1: csr_build v3 — 1024 threads (R8 proven) + PADDED rows: each CSR
// row padded to a multiple of 4 slots with (col=gbase, val=0) so the gather
// inner loop needs ZERO per-slot predication (fmaf(0,x,acc)==acc exactly).
// Two-level wave scan over padded counts; pad slots filled in LDS alongside
// placement (disjoint indices); padded coalesced writeout.
// ---------------------------------------------------------------------------
__global__ __launch_bounds__(1024) void csr_build(
    const int* __restrict__ rG, const int* __restrict__ cG, const float* __restrict__ vG,
    const int* __restrict__ rB, const int* __restrict__ cB, const float* __restrict__ vB,
    const int* __restrict__ r1, const int* __restrict__ c1, const float* __restrict__ v1,
    const int* __restrict__ r2, const int* __restrict__ c2, const float* __restrict__ v2,
    int* __restrict__ offs_out, int2* __restrict__ pairs_out)
{
    __shared__ int   scount[N_NODES];
    __shared__ int   soffs[N_NODES+1];
    __shared__ int   scursor[N_NODES];
    __shared__ int   scol[PPAD];
    __shared__ float sval[PPAD];
    __shared__ int   swsum[16];
    __shared__ int   swoff[16];
    __shared__ int   stot;

    int bid = blockIdx.x;
    int tid = threadIdx.x;
    int lane = tid & 63, w = tid >> 6;
    int g = bid & 127;
    int m = bid >> 7;
    const int*   rows = (m==0)?rG:(m==1)?rB:(m==2)?r1:r2;
    const int*   cols = (m==0)?cG:(m==1)?cB:(m==2)?c1:c2;
    const float* vals = (m==0)?vG:(m==1)?vB:(m==2)?v1:v2;

    int ebase = g*EPG;
    int gbase = g*N_NODES;
    int seg = m*N_GRAPH + g;

    if (tid < N_NODES) scount[tid] = 0;
    __syncthreads();
    for (int i = tid; i < EPG; i += 1024)
        atomicAdd(&scount[rows[ebase+i] - gbase], 1);
    __syncthreads();

    // two-level exclusive scan over PADDED counts
    int cnt  = (tid < N_NODES) ? scount[tid] : 0;
    int pcnt = (cnt + 3) & ~3;
    int v = pcnt;
    #pragma unroll
    for (int d = 1; d < 64; d <<= 1) {
        int t = __shfl_up(v, (unsigned)d, 64);
        if (lane >= d) v += t;
    }
    if (lane == 63) swsum[w] = v;
    __syncthreads();
    if (w == 0 && lane < 16) {
        int s = swsum[lane];
        #pragma unroll
        for (int d = 1; d < 16; d <<= 1) {
            int t = __shfl_up(s, (unsigned)d, 16);
            if ((lane & 15) >= d) s += t;
        }
        swoff[lane] = s - swsum[lane];     // exclusive wave offset
        if (lane == 15) stot = s;          // padded total
    }
    __syncthreads();
    int excl = v - pcnt + swoff[w];
    if (tid < N_NODES) { soffs[tid] = excl; scursor[tid] = excl; }
    if (tid == 0) soffs[N_NODES] = stot;
    __syncthreads();

    // placement of real pairs + pad-slot fill (disjoint indices, no race)
    for (int i = tid; i < EPG; i += 1024) {
        int r = rows[ebase+i] - gbase;
        int pos = atomicAdd(&scursor[r], 1);
        scol[pos] = cols[ebase+i];
        sval[pos] = vals[ebase+i];
    }
    for (int i = tid; i < N_NODES; i += 1024) {
        int d = scount[i];
        int s0 = soffs[i] + d, e0 = soffs[i] + ((d + 3) & ~3);
        for (int k = s0; k < e0; ++k) { scol[k] = gbase; sval[k] = 0.f; }
    }
    __syncthreads();

    int total = soffs[N_NODES];
    if (tid <= N_NODES) offs_out[(size_t)seg*OSTR + tid] = soffs[tid];
    int2* po = pairs_out + (size_t)seg*PSTR;
    for (int i = tid; i < total; i += 1024)
        po[i] = make_int2(scol[i], __float_as_int(sval[i]));
}

// ---------------------------------------------------------------------------
__device__ __forceinline__ void node_math1(
    float ev, float fv, float gd, float bd, float pd, float qd,
    float eGv, float fGv, float eBv, float fBv,
    float& e3v, float& nev, float& f3v, float& nfv)
{
    float invb = 1.0f/(ev*ev + fv*fv + 0.1f);
    float alpha = (pd*ev + qd*fv)*invb - eGv - fBv;
    float beta  = (qd*ev - pd*fv)*invb + fGv + eBv;
    float invg = 1.0f/(gd*gd + bd*bd);
    e3v = (alpha*gd + beta*bd)*invg;
    f3v = (beta*gd - alpha*bd)*invg;
    float bb1 = eGv - fBv, bb2 = fGv + eBv;
    float vv = ev*ev + fv*fv;
    float P_ = pd - vv*gd, Q_ = qd + vv*bd;
    nev = (P_*bb1 + Q_*bb2)*invg;
    nfv = (P_*bb2 - Q_*bb1)*invg;
}

// ---------------------------------------------------------------------------
// Kernel 2: gather SpMM v8 — padded CSR, ZERO per-slot predication. 4-slot
// chunks; pair loads are wave-uniform scalar loads; one efh gather + 4 fma
// per slot; per-stream wave-uniform guards only (s_cbranch). A/B streams
// interleaved per chunk -> up to 8 gathers + 8 scalar loads in flight.
// arrs: [0]=e3 [1]=ne [2]=e1 [3]=e2 [4]=f3 [5]=nf [6]=f1 [7]=f2
// Grid: 2816 = 8 XCD * 16 graphs * 22 (11 tiles x 2 sets).
// ---------------------------------------------------------------------------
__global__ __launch_bounds__(256) void gather_all(
    const float* __restrict__ e, const float* __restrict__ f,
    const unsigned* __restrict__ efh,
    const float* __restrict__ Gd, const float* __restrict__ Bd,
    const float* __restrict__ Pd, const float* __restrict__ Qd,
    const float* __restrict__ w_ae, const float* __restrict__ w_af,
    const int* __restrict__ offs, const int2* __restrict__ pairs,
    unsigned* __restrict__ arrs, float* __restrict__ partials)
{
    int tid = threadIdx.x, lane = tid & 63, wv = tid >> 6;
    int bid = blockIdx.x;
    int xcd = bid & 7, loc = bid >> 3;          // loc 0..351
    int g    = xcd*16 + loc/22;
    int sub  = loc % 22;
    int set  = (sub < NTILE) ? 0 : 1;
    int tile = sub - set*NTILE;
    int r0   = tile*TROWS;
    int rlim = min(TROWS, N_NODES - r0);
    int mA = set ? 2 : 0, mB = set ? 3 : 1;

    const int*  poA = offs + (size_t)(mA*N_GRAPH + g)*OSTR;
    const int*  poB = offs + (size_t)(mB*N_GRAPH + g)*OSTR;
    const int2* ppA = pairs + (size_t)(mA*N_GRAPH + g)*PSTR;
    const int2* ppB = pairs + (size_t)(mB*N_GRAPH + g)*PSTR;

    float wa = w_ae[lane], wf = w_af[lane];
    float pa0 = 0.f, pa1 = 0.f, pa2 = 0.f, pa3 = 0.f;

    for (int lr = wv; lr < rlim; lr += 4) {
        int r = r0 + lr;
        int node = g*N_NODES + r;
        int sA = __builtin_amdgcn_readfirstlane(poA[r]);
        int tA = __builtin_amdgcn_readfirstlane(poA[r+1]);
        int sB = __builtin_amdgcn_readfirstlane(poB[r]);
        int tB = __builtin_amdgcn_readfirstlane(poB[r+1]);
        int dA = tA - sA, dB = tB - sB;        // multiples of 4 (padded)
        int nmax = max(dA, dB);

        float aE = 0.f, aF = 0.f, bE = 0.f, bF = 0.f;

        for (int base = 0; base < nmax; base += 4) {
            bool hA = base < dA, hB = base < dB;   // wave-uniform
            int2 qA[4], qB[4];
            unsigned uA[4], uB[4];
            if (hA) {
                #pragma unroll
                for (int j = 0; j < 4; ++j) qA[j] = ppA[sA + base + j];
            }
            if (hB) {
                #pragma unroll
                for (int j = 0; j < 4; ++j) qB[j] = ppB[sB + base + j];
            }
            if (hA) {
                #pragma unroll
                for (int j = 0; j < 4; ++j) uA[j] = efh[((unsigned)qA[j].x << 6) + (unsigned)lane];
            }
            if (hB) {
                #pragma unroll
                for (int j = 0; j < 4; ++j) uB[j] = efh[((unsigned)qB[j].x << 6) + (unsigned)lane];
            }
            if (hA) {
                #pragma unroll
                for (int j = 0; j < 4; ++j) {
                    float v = __int_as_float(qA[j].y);
                    aE = fmaf(v, __uint_as_float(uA[j] & 0xFFFF0000u), aE);
                    aF = fmaf(v, __uint_as_float(uA[j] << 16), aF);
                }
            }
            if (hB) {
                #pragma unroll
                for (int j = 0; j < 4; ++j) {
                    float v = __int_as_float(qB[j].y);
                    bE = fmaf(v, __uint_as_float(uB[j] & 0xFFFF0000u), bE);
                    bF = fmaf(v, __uint_as_float(uB[j] << 16), bF);
                }
            }
        }

        size_t idx = (size_t)node*FDIM + lane;
        if (set == 0) {
            float ev = e[idx], fv = f[idx];
            float gd = Gd[node], bd = Bd[node], pd = Pd[node], qd = Qd[node];
            float e3v, nev, f3v, nfv;
            node_math1(ev, fv, gd, bd, pd, qd, aE, aF, bE, bF, e3v, nev, f3v, nfv);
            arrs[0*NF + idx] = pack_bf(e3v);
            arrs[1*NF + idx] = pack_bf(nev);
            arrs[4*NF + idx] = pack_bf(f3v);
            arrs[5*NF + idx] = pack_bf(nfv);
            pa0 += e3v*wa; pa1 += nev*wa; pa2 += f3v*wf; pa3 += nfv*wf;
        } else {
            arrs[2*NF + idx] = pack_bf(aE);   // e1
            arrs[3*NF + idx] = pack_bf(bE);   // e2
            arrs[6*NF + idx] = pack_bf(aF);   // f1
            arrs[7*NF + idx] = pack_bf(bF);   // f2
            pa0 += aE*wa; pa1 += bE*wa; pa2 += aF*wf; pa3 += bF*wf;
        }
    }

    __shared__ float sred[4];
    if (tid < 4) sred[tid] = 0.f;
    __syncthreads();
    #pragma unroll
    for (int off = 32; off > 0; off >>= 1) {
        pa0 += __shfl_down(pa0, off); pa1 += __shfl_down(pa1, off);
        pa2 += __shfl_down(pa2, off); pa3 += __shfl_down(pa3, off);
    }
    if (lane == 0) {
        atomicAdd(&sred[0], pa0); atomicAdd(&sred[1], pa1);
        atomicAdd(&sred[2], pa2); atomicAdd(&sred[3], pa3);
    }
    __syncthreads();
    if (tid == 0) {
        float* pt = partials + ((size_t)g*NTILE + tile)*8;
        if (set == 0) { pt[0] = sred[0]; pt[1] = sred[1]; pt[4] = sred[2]; pt[5] = sred[3]; }
        else          { pt[2] = sred[0]; pt[3] = sred[1]; pt[6] = sred[2]; pt[7] = sred[3]; }
    }
}

// ---------------------------------------------------------------------------
// Kernel 3: finalize attention weights (normalized)
// ---------------------------------------------------------------------------
__global__ void attn_final(const float* __restrict__ partials,
                           const float* __restrict__ b_ae, const float* __restrict__ b_af,
                           float* __restrict__ att)
{
    int g = threadIdx.x;
    if (g >= N_GRAPH) return;
    float s[8];
    #pragma unroll
    for (int j = 0; j < 8; ++j) {
        float t = 0.f;
        for (int q = 0; q < NTILE; ++q) t += partials[((size_t)g*NTILE + q)*8 + j];
        s[j] = t;
    }
    float ae[4], af[4], se = 1e-4f, sf = 1e-4f;
    float bae = b_ae[0], baf = b_af[0];
    #pragma unroll
    for (int j = 0; j < 4; ++j) {
        float x = s[j]*(1.0f/N_NODES) + bae;
        ae[j] = 1.0f/(1.0f + expf(-x)); se += ae[j];
        float y = s[4+j]*(1.0f/N_NODES) + baf;
        af[j] = 1.0f/(1.0f + expf(-y)); sf += af[j];
    }
    #pragma unroll
    for (int j = 0; j < 4; ++j) {
        att[g*8 + j]     = ae[j]/se;
        att[g*8 + 4 + j] = af[j]/sf;
    }
}

// ---------------------------------------------------------------------------
// Kernel 4: MFMA epilogue (round-1/6 proven). Stage packed-bf16 uints into
// LDS in fragment order (10 segs: e3,ne,e1,e2,e | f3,nf,f1,f2,f), unpack
// hi/lo with shifts, 5 per-segment accumulators, att folded post-MFMA,
// tanh + store. LDS slot layout: [seg*8+(feat>>3)][node 0..15][8], stride 132.
// ---------------------------------------------------------------------------
__global__ __launch_bounds__(256) void final_fused(
    const float* __restrict__ e, const float* __restrict__ f,
    const unsigned* __restrict__ arrs, const float* __restrict__ att,
    const unsigned short* __restrict__ Wb1h, const unsigned short* __restrict__ Wb1l,
    const unsigned short* __restrict__ Wb2h, const unsigned short* __restrict__ Wb2l,
    const float* __restrict__ bv1, const float* __restrict__ bv2,
    float* __restrict__ out)
{
    __shared__ __align__(16) unsigned sfrag[80*132];

    int tid = threadIdx.x, lane = tid & 63, chunk = tid >> 6;
    int node0 = blockIdx.x * 16;
    int sl = lane >> 3, jj = lane & 7;

    #pragma unroll
    for (int round = 0; round < 4; ++round) {
        int ni = round*4 + chunk;
        size_t idx = (size_t)(node0 + ni)*FDIM + lane;
        #pragma unroll
        for (int seg = 0; seg < 10; ++seg) {
            unsigned u;
            if (seg == 4)      u = pack_bf(e[idx]);
            else if (seg == 9) u = pack_bf(f[idx]);
            else {
                int a = (seg < 4) ? seg : seg - 1;   // segs 0..3 -> arrs0..3; 5..8 -> arrs4..7
                u = arrs[(size_t)a*NF + idx];
            }
            sfrag[(seg*8 + sl)*132 + ni*8 + jj] = u;
        }
    }
    __syncthreads();

    int m16 = lane & 15, quad = lane >> 4;
    float4v acce[5], accf[5];
    #pragma unroll
    for (int s = 0; s < 5; ++s) {
        acce[s] = (float4v){0.f,0.f,0.f,0.f};
        accf[s] = (float4v){0.f,0.f,0.f,0.f};
    }

    #pragma unroll
    for (int seg = 0; seg < 5; ++seg) {
        #pragma unroll
        for (int ks2 = 0; ks2 < 2; ++ks2) {
            int ks = seg*2 + ks2;
            size_t boff = (size_t)((ks*4 + chunk)*64 + lane)*8;
            // e-side
            {
                const unsigned* pa = &sfrag[(seg*8 + ks2*4 + quad)*132 + m16*8];
                uint4 ua = *(const uint4*)pa;
                uint4 ub = *(const uint4*)(pa + 4);
                unsigned uu[8] = {ua.x,ua.y,ua.z,ua.w,ub.x,ub.y,ub.z,ub.w};
                short8 ah, al;
                #pragma unroll
                for (int j = 0; j < 8; ++j) {
                    ah[j] = (short)(uu[j] >> 16);
                    al[j] = (short)(uu[j] & 0xFFFFu);
                }
                short8 bh = *(const short8*)(Wb1h + boff);
                short8 bl = *(const short8*)(Wb1l + boff);
                acce[seg] = __builtin_amdgcn_mfma_f32_16x16x32_bf16(ah, bh, acce[seg], 0, 0, 0);
                acce[seg] = __builtin_amdgcn_mfma_f32_16x16x32_bf16(al, bh, acce[seg], 0, 0, 0);
                acce[seg] = __builtin_amdgcn_mfma_f32_16x16x32_bf16(ah, bl, acce[seg], 0, 0, 0);
            }
            // f-side
            {
                const unsigned* pa = &sfrag[((seg+5)*8 + ks2*4 + quad)*132 + m16*8];
                uint4 ua = *(const uint4*)pa;
                uint4 ub = *(const uint4*)(pa + 4);
                unsigned uu[8] = {ua.x,ua.y,ua.z,ua.w,ub.x,ub.y,ub.z,ub.w};
                short8 ch, cl;
                #pragma unroll
                for (int j = 0; j < 8; ++j) {
                    ch[j] = (short)(uu[j] >> 16);
                    cl[j] = (short)(uu[j] & 0xFFFFu);
                }
                short8 bh = *(const short8*)(Wb2h + boff);
                short8 bl = *(const short8*)(Wb2l + boff);
                accf[seg] = __builtin_amdgcn_mfma_f32_16x16x32_bf16(ch, bh, accf[seg], 0, 0, 0);
                accf[seg] = __builtin_amdgcn_mfma_f32_16x16x32_bf16(cl, bh, accf[seg], 0, 0, 0);
                accf[seg] = __builtin_amdgcn_mfma_f32_16x16x32_bf16(ch, bl, accf[seg], 0, 0, 0);
            }
        }
    }

    int o = chunk*16 + m16;
    float be = bv1[o], bf = bv2[o];
    #pragma unroll
    for (int reg = 0; reg < 4; ++reg) {
        int node = node0 + quad*4 + reg;
        int g = node / N_NODES;
        float se2 = acce[4][reg];
        float sf2 = accf[4][reg];
        #pragma unroll
        for (int b = 0; b < 4; ++b) {
            se2 = fmaf(att[g*8 + b],     acce[b][reg], se2);
            sf2 = fmaf(att[g*8 + 4 + b], accf[b][reg], sf2);
        }
        out[(size_t)node*FDIM + o]      = tanhf(se2 + be);
        out[NF + (size_t)node*FDIM + o] = tanhf(sf2 + bf);
    }
}

// ---------------------------------------------------------------------------
extern "C" void kernel_launch(void* const* d_in, const int* in_sizes, int n_in,
                              void* d_out, int out_size, void* d_ws, size_t ws_size,
                              hipStream_t stream) {
    (void)in_sizes; (void)n_in; (void)out_size; (void)ws_size;
    const float* e     = (const float*)d_in[0];
    const float* f     = (const float*)d_in[1];
    const int*   rowsG = (const int*)d_in[2];
    const int*   colsG = (const int*)d_in[3];
    const float* valsG = (const float*)d_in[4];
    const int*   rowsB = (const int*)d_in[5];
    const int*   colsB = (const int*)d_in[6];
    const float* valsB = (const float*)d_in[7];
    const int*   rows1 = (const int*)d_in[8];
    const int*   cols1 = (const int*)d_in[9];
    const float* vals1 = (const float*)d_in[10];
    const int*   rows2 = (const int*)d_in[11];
    const int*   cols2 = (const int*)d_in[12];
    const float* vals2 = (const float*)d_in[13];
    const float* G_d   = (const float*)d_in[14];
    const float* B_d   = (const float*)d_in[15];
    const float* Pd    = (const float*)d_in[16];
    const float* Qd    = (const float*)d_in[17];
    const float* W1    = (const float*)d_in[18];
    const float* b1    = (const float*)d_in[19];
    const float* W2    = (const float*)d_in[20];
    const float* b2    = (const float*)d_in[21];
    const float* w_ae  = (const float*)d_in[22];
    const float* b_ae  = (const float*)d_in[23];
    const float* w_af  = (const float*)d_in[24];
    const float* b_af  = (const float*)d_in[25];

    unsigned* arrs  = (unsigned*)d_ws;               // 8*NF uints (packed bf16 h|l)
    float* partials = (float*)(arrs + 8*NF);         // 128*11*8 = 11264
    float* att      = partials + 11264;              // 1024 (normalized weights)
    unsigned short* Wb1h = (unsigned short*)(att + 1024);  // 20480 shorts each
    unsigned short* Wb1l = Wb1h + 20480;
    unsigned short* Wb2h = Wb1l + 20480;
    unsigned short* Wb2l = Wb2h + 20480;
    int*   offs     = (int*)(Wb2l + 20480);          // 512*OSTR ints
    int2*  pairs    = (int2*)(offs + 512*OSTR);      // 512*PSTR int2 (padded CSR)
    unsigned* efh   = (unsigned*)(pairs + (size_t)512*PSTR);  // NF uints (bf16 e|f pairs)

    prep_pack<<<dim3(80 + PACKB), dim3(256), 0, stream>>>(
        W1, W2, e, f, Wb1h, Wb1l, Wb2h, Wb2l, efh);

    csr_build<<<dim3(512), dim3(1024), 0, stream>>>(
        rowsG, colsG, valsG, rowsB, colsB, valsB,
        rows1, cols1, vals1, rows2, cols2, vals2, offs, pairs);

    gather_all<<<dim3(2816), dim3(256), 0, stream>>>(
        e, f, efh, G_d, B_d, Pd, Qd, w_ae, w_af, offs, pairs, arrs, partials);

    attn_final<<<dim3(1), dim3(128), 0, stream>>>(partials, b_ae, b_af, att);

    final_fused<<<dim3(NTOT/16), dim3(256), 0, stream>>>(
        e, f, arrs, att, Wb1h, Wb1l, Wb2h, Wb2l, b1, b2, (float*)d_out);
}